// Round 2
// baseline (94.790 us; speedup 1.0000x reference)
//
#include <hip/hip_runtime.h>
#include <math.h>

// Problem constants (fixed by the reference)
constexpr int IN_DIM  = 128;
constexpr int OUT_DIM = 128;
constexpr int BATCH   = 512;
// Fused single kernel, high-occupancy variant:
//   block = 8 n x 16 o cells x 4 i-groups = 512 threads (8 waves)
//   grid  = 64 n-tiles x 8 o-tiles = 512 blocks = exactly 2 blocks/CU
//   -> 16 waves/CU (same TLP as the original two-kernel pipeline), one dispatch,
//      no d_ws partials, no mid-loop barriers (coef streamed from L2).
constexpr int TN  = 8;
constexpr int TO  = 16;
constexpr int IG  = 4;              // in-block i-reduction split
constexpr int IPT = IN_DIM / IG;    // 32 i per thread
// LDS padding: +pad rows kill power-of-2 bank strides while keeping 16B align.
constexpr int PSR = 2 * IN_DIM + 1; // float4 stride per n-row of basis (257)
constexpr int SR  = IN_DIM + 4;     // float stride per row of scalar tiles (132)

// out[n,o] = sum_i mask[s]*( scale_base[s]*silu(x[n,i])
//                          + scale_sp[s]*sum_j B_j(x[n,i])*coef[s,j] ), s=o*128+i
__global__ __launch_bounds__(512, 4) void kan_fused(
    const float* __restrict__ x,          // [512][128]
    const float* __restrict__ grid,       // [16384][6] (rows identical)
    const float* __restrict__ coef,       // [16384][8]
    const float* __restrict__ scale_base, // [16384]
    const float* __restrict__ scale_sp,   // [16384]
    const float* __restrict__ mask,       // [16384]
    float* __restrict__ out)              // [512][128]
{
    __shared__ float4 Ps[TN * PSR];       // 32.9 KB basis fragments, [n][i][2], padded
    __shared__ float  Pb[TN * SR];        //  4.2 KB silu(x), [n][i]
    __shared__ float  Sm[TO * SR];        //  8.4 KB scale_sp*mask, [o][i]
    __shared__ float  Vb[TO * SR];        //  8.4 KB scale_base*mask, [o][i]
    __shared__ float  Red[IG * TN * TO];  //  2.0 KB ig-partials           (~56 KB total)

    const int t  = threadIdx.x;
    const int b  = blockIdx.x;
    // otile = b & 7 == XCD id under default round-robin placement: all 64 blocks
    // reading one 64 KB coef slice share that XCD's L2.
    const int o0 = (b & 7) * TO;
    const int n0 = (b >> 3) * TN;

    // ---- knots from row 0 (all grid rows identical, uniform spacing h)
    const float g0 = grid[0];
    const float g5 = grid[5];
    const float h  = (g5 - g0) * 0.2f;
    float tk[12];
    tk[0] = g0 - 3.f * h; tk[1] = g0 - 2.f * h; tk[2] = g0 - h;
    tk[3] = grid[0]; tk[4] = grid[1]; tk[5] = grid[2];
    tk[6] = grid[3]; tk[7] = grid[4]; tk[8] = grid[5];
    tk[9] = g5 + h; tk[10] = g5 + 2.f * h; tk[11] = g5 + 3.f * h;
    // Uniform knots: every Cox-de Boor denominator is exactly r*h.
    const float inv1 = 1.0f / h;
    const float invr[3] = {inv1, inv1 * 0.5f, inv1 * (1.0f / 3.0f)};

    // ---- phase 1a: basis + silu for 8 n x 128 i (2 evals/thread)
    #pragma unroll
    for (int r = 0; r < 2; r++) {
        const int v = r * 512 + t;
        const int n = v >> 7;          // 0..7
        const int i = v & 127;         // coalesced x reads
        const float xv = x[(n0 + n) * IN_DIM + i];
        float B[11];
        #pragma unroll
        for (int j = 0; j < 11; j++)
            B[j] = (xv >= tk[j] && xv < tk[j + 1]) ? 1.0f : 0.0f;
        #pragma unroll
        for (int rr = 1; rr <= 3; rr++) {
            const float iv = invr[rr - 1];
            #pragma unroll
            for (int j = 0; j + rr < 11; j++)
                B[j] = (xv - tk[j]) * iv * B[j] + (tk[j + rr + 1] - xv) * iv * B[j + 1];
        }
        Ps[n * PSR + 2 * i + 0] = make_float4(B[0], B[1], B[2], B[3]);
        Ps[n * PSR + 2 * i + 1] = make_float4(B[4], B[5], B[6], B[7]);
        Pb[n * SR + i] = xv / (1.0f + __expf(-xv));   // silu
    }

    // ---- phase 1b: scalar tiles ssp*mask, sb*mask for 16 o x 128 i (coalesced)
    #pragma unroll
    for (int r = 0; r < 4; r++) {
        const int v = r * 512 + t;     // 0..2047
        const int o = v >> 7;
        const int i = v & 127;
        const int s = (o0 + o) * IN_DIM + i;
        const float mv = mask[s];
        Sm[o * SR + i] = scale_sp[s]   * mv;
        Vb[o * SR + i] = scale_base[s] * mv;
    }
    __syncthreads();   // the only barrier before the epilogue

    // ---- main loop: barrier-free. coef streamed from L2 (512 KB, XCD-resident),
    // basis/scalars from LDS. Per 8-i group: 6 scalar b128 + 16 basis b128 reads,
    // all conflict-free or free 2-way (pads chosen for 4n/16o lane patterns).
    const int o  = t & 15;
    const int n  = (t >> 4) & 7;
    const int ig = t >> 7;             // 0..3
    const float4* __restrict__ cf  = (const float4*)coef;
    const float4* __restrict__ psn = &Ps[n * PSR];
    const float*  __restrict__ pbn = &Pb[n * SR];
    const float*  __restrict__ smo = &Sm[o * SR];
    const float*  __restrict__ vbo = &Vb[o * SR];
    const size_t  crow = (size_t)(o0 + o) * IN_DIM;
    const int     ibase = ig * IPT;

    float acc = 0.f;
    #pragma unroll 1
    for (int g = 0; g < IPT / 8; g++) {
        const int i8 = ibase + g * 8;
        const float4 sm0 = *(const float4*)&smo[i8];
        const float4 sm1 = *(const float4*)&smo[i8 + 4];
        const float4 vb0 = *(const float4*)&vbo[i8];
        const float4 vb1 = *(const float4*)&vbo[i8 + 4];
        const float4 pb0 = *(const float4*)&pbn[i8];
        const float4 pb1 = *(const float4*)&pbn[i8 + 4];
        const float sm_[8] = {sm0.x, sm0.y, sm0.z, sm0.w, sm1.x, sm1.y, sm1.z, sm1.w};
        const float vb_[8] = {vb0.x, vb0.y, vb0.z, vb0.w, vb1.x, vb1.y, vb1.z, vb1.w};
        const float pb_[8] = {pb0.x, pb0.y, pb0.z, pb0.w, pb1.x, pb1.y, pb1.z, pb1.w};
        #pragma unroll
        for (int il = 0; il < 8; il++) {       // static indices -> registers
            const int i = i8 + il;
            const float4 c0 = cf[(crow + i) * 2 + 0];
            const float4 c1 = cf[(crow + i) * 2 + 1];
            const float4 a0 = psn[2 * i];
            const float4 a1 = psn[2 * i + 1];
            const float w = c0.x * a0.x + c0.y * a0.y + c0.z * a0.z + c0.w * a0.w
                          + c1.x * a1.x + c1.y * a1.y + c1.z * a1.z + c1.w * a1.w;
            acc = fmaf(sm_[il], w, acc);
            acc = fmaf(vb_[il], pb_[il], acc);
        }
    }

    // ---- epilogue: 4-way ig reduction in LDS, coalesced store
    Red[ig * (TN * TO) + (n * TO + o)] = acc;
    __syncthreads();
    if (t < TN * TO) {
        const float s = Red[t] + Red[128 + t] + Red[256 + t] + Red[384 + t];
        const int n2 = t >> 4;
        const int o2 = t & 15;
        out[(size_t)(n0 + n2) * OUT_DIM + o0 + o2] = s;
    }
}

extern "C" void kernel_launch(void* const* d_in, const int* in_sizes, int n_in,
                              void* d_out, int out_size, void* d_ws, size_t ws_size,
                              hipStream_t stream) {
    (void)in_sizes; (void)n_in; (void)out_size; (void)d_ws; (void)ws_size;
    const float* x          = (const float*)d_in[0];
    const float* grid       = (const float*)d_in[1];
    const float* coef       = (const float*)d_in[2];
    const float* scale_base = (const float*)d_in[3];
    const float* scale_sp   = (const float*)d_in[4];
    const float* mask       = (const float*)d_in[5];

    // 64 n-tiles x 8 o-tiles = 512 blocks, 512 threads: 2 blocks/CU, 16 waves/CU
    kan_fused<<<dim3(512), dim3(512), 0, stream>>>(
        x, grid, coef, scale_base, scale_sp, mask, (float*)d_out);
}

// Round 3
// 74.025 us; speedup vs baseline: 1.2805x; 1.2805x over previous
//
#include <hip/hip_runtime.h>
#include <math.h>

// Problem constants (fixed by the reference)
constexpr int IN_DIM  = 128;
constexpr int OUT_DIM = 128;
constexpr int BATCH   = 512;
// Tiling: block = 16 n x 128 o x 4 i; thread = 4 n x 2 o cells (8 accs).
// grid = 32 n-tiles x 32 i-chunks = 1024 blocks = 4/CU -> 16 waves/CU (as R0).
// Per wave per i: 4 Cs b128 (conflict-free) + 8 Ps b128 (wave-uniform bcast)
// + 2 Vb b32 + 4 Pb b32 = 18 LDS reads for 8 cells (R0 was 9 for 2).
constexpr int TN     = 16;            // n per block
constexpr int IC     = 4;             // i per block (chunk)
constexpr int NCHUNK = IN_DIM / IC;   // 32 chunks
constexpr int PCS    = 130;           // float4 stride per i-row of Cs (128+2)
constexpr int PVB    = 132;           // float  stride per i-row of Vb
constexpr int PPS    = 9;             // float4 stride per n-row of Ps (4i*2+1)

// out[n,o] = sum_i mask[s]*( scale_base[s]*silu(x[n,i])
//                          + scale_sp[s]*sum_j B_j(x[n,i])*coef[s,j] ), s=o*128+i
__global__ __launch_bounds__(256, 4) void kan_main(
    const float* __restrict__ x,          // [512][128]
    const float* __restrict__ grid,       // [16384][6] (rows identical)
    const float* __restrict__ coef,       // [16384][8]
    const float* __restrict__ scale_base, // [16384]
    const float* __restrict__ scale_sp,   // [16384]
    const float* __restrict__ mask,       // [16384]
    float* __restrict__ part)             // [32][512][128] partials in d_ws
{
    __shared__ float4 Cs0[IC * PCS];   // 8.3 KB coef j0..3 * ssp * mask, [i][o]
    __shared__ float4 Cs1[IC * PCS];   // 8.3 KB coef j4..7 * ssp * mask
    __shared__ float  Vb [IC * PVB];   // 2.1 KB scale_base*mask, [i][o]
    __shared__ float4 Ps [TN * PPS];   // 2.3 KB basis fragments, [n][i][2]
    __shared__ float  Pb [TN * IC];    // 0.3 KB silu(x), [n][i]      (~21.3 KB)

    const int t     = threadIdx.x;
    const int b     = blockIdx.x;
    const int chunk = b & 31;
    const int nt    = b >> 5;
    const int i0    = chunk * IC;
    const int n0    = nt * TN;

    // ---- knots from row 0 (all grid rows identical, uniform spacing h)
    const float g0 = grid[0];
    const float g5 = grid[5];
    const float h  = (g5 - g0) * 0.2f;
    float tk[12];
    tk[0] = g0 - 3.f * h; tk[1] = g0 - 2.f * h; tk[2] = g0 - h;
    tk[3] = grid[0]; tk[4] = grid[1]; tk[5] = grid[2];
    tk[6] = grid[3]; tk[7] = grid[4]; tk[8] = grid[5];
    tk[9] = g5 + h; tk[10] = g5 + 2.f * h; tk[11] = g5 + 3.f * h;
    // Uniform knots: every Cox-de Boor denominator is exactly r*h.
    const float inv1 = 1.0f / h;
    const float invr[3] = {inv1, inv1 * 0.5f, inv1 * (1.0f / 3.0f)};

    // ---- phase 1: basis + silu for 16 n x 4 i (threads 0..63)
    if (t < TN * IC) {
        const int n = t >> 2;
        const int i = t & 3;
        const float xv = x[(n0 + n) * IN_DIM + i0 + i];
        float B[11];
        #pragma unroll
        for (int j = 0; j < 11; j++)
            B[j] = (xv >= tk[j] && xv < tk[j + 1]) ? 1.0f : 0.0f;
        #pragma unroll
        for (int rr = 1; rr <= 3; rr++) {
            const float iv = invr[rr - 1];
            #pragma unroll
            for (int j = 0; j + rr < 11; j++)
                B[j] = (xv - tk[j]) * iv * B[j] + (tk[j + rr + 1] - xv) * iv * B[j + 1];
        }
        Ps[n * PPS + 2 * i + 0] = make_float4(B[0], B[1], B[2], B[3]);
        Ps[n * PPS + 2 * i + 1] = make_float4(B[4], B[5], B[6], B[7]);
        Pb[n * IC + i] = xv / (1.0f + __expf(-xv));   // silu
    }

    // ---- stage coef premultiplied by scale_sp*mask.
    // 128 o x 4 i x 2 halves = 1024 float4 -> 4 reps. Consecutive lanes cover
    // (half,i) = 128 B contiguous per o-row: fully-used 64B transactions.
    #pragma unroll
    for (int r = 0; r < 4; r++) {
        const int fi = r * 256 + t;
        const int hh = fi & 1;
        const int i  = (fi >> 1) & 3;
        const int o  = fi >> 3;
        const int s  = o * IN_DIM + i0 + i;
        float4 c = ((const float4*)coef)[(size_t)s * 2 + hh];
        const float v = scale_sp[s] * mask[s];
        c.x *= v; c.y *= v; c.z *= v; c.w *= v;
        if (hh) Cs1[i * PCS + o] = c; else Cs0[i * PCS + o] = c;
    }
    // ---- stage scale_base*mask: 128 o x 4 i
    #pragma unroll
    for (int r = 0; r < 2; r++) {
        const int v = r * 256 + t;
        const int i = v & 3;
        const int o = v >> 2;
        const int s = o * IN_DIM + i0 + i;
        Vb[i * PVB + o] = scale_base[s] * mask[s];
    }
    __syncthreads();   // the only barrier

    // ---- main: pure LDS + FMA, barrier-free. Thread = (ol, ol+64) x 4 n.
    // n is wave-uniform (t>>6), so all Ps/Pb reads are broadcast.
    const int ol  = t & 63;
    const int ng  = t >> 6;            // 0..3, uniform per wave
    const int nb  = ng * 4;            // first of this wave's 4 n

    float accA[4] = {0.f, 0.f, 0.f, 0.f};   // o = ol
    float accB[4] = {0.f, 0.f, 0.f, 0.f};   // o = ol + 64
    #pragma unroll
    for (int il = 0; il < IC; il++) {
        const float4 c0a = Cs0[il * PCS + ol];
        const float4 c1a = Cs1[il * PCS + ol];
        const float4 c0b = Cs0[il * PCS + ol + 64];
        const float4 c1b = Cs1[il * PCS + ol + 64];
        const float  vba = Vb[il * PVB + ol];
        const float  vbb = Vb[il * PVB + ol + 64];
        #pragma unroll
        for (int k = 0; k < 4; k++) {
            const int n = nb + k;
            const float4 a0 = Ps[n * PPS + 2 * il + 0];
            const float4 a1 = Ps[n * PPS + 2 * il + 1];
            const float  pb = Pb[n * IC + il];
            const float wA = c0a.x * a0.x + c0a.y * a0.y + c0a.z * a0.z + c0a.w * a0.w
                           + c1a.x * a1.x + c1a.y * a1.y + c1a.z * a1.z + c1a.w * a1.w;
            const float wB = c0b.x * a0.x + c0b.y * a0.y + c0b.z * a0.z + c0b.w * a0.w
                           + c1b.x * a1.x + c1b.y * a1.y + c1b.z * a1.z + c1b.w * a1.w;
            accA[k] += wA + vba * pb;
            accB[k] += wB + vbb * pb;
        }
    }

    // coalesced partial stores (lanes consecutive in o within each wave)
    #pragma unroll
    for (int k = 0; k < 4; k++) {
        const size_t row = (size_t)chunk * BATCH + (n0 + nb + k);
        part[row * OUT_DIM + ol]      = accA[k];
        part[row * OUT_DIM + ol + 64] = accB[k];
    }
}

// Sum the 32 i-chunk partials. 64K cells, fully coalesced.
__global__ __launch_bounds__(256) void kan_reduce(
    const float* __restrict__ part,   // [32][65536]
    float* __restrict__ out)          // [65536]
{
    const int cell = blockIdx.x * 256 + threadIdx.x;
    float s = 0.f;
    #pragma unroll
    for (int c = 0; c < NCHUNK; c++)
        s += part[(size_t)c * (BATCH * OUT_DIM) + cell];
    out[cell] = s;
}

extern "C" void kernel_launch(void* const* d_in, const int* in_sizes, int n_in,
                              void* d_out, int out_size, void* d_ws, size_t ws_size,
                              hipStream_t stream) {
    (void)in_sizes; (void)n_in; (void)out_size; (void)ws_size;
    const float* x          = (const float*)d_in[0];
    const float* grid       = (const float*)d_in[1];
    const float* coef       = (const float*)d_in[2];
    const float* scale_base = (const float*)d_in[3];
    const float* scale_sp   = (const float*)d_in[4];
    const float* mask       = (const float*)d_in[5];
    float* out  = (float*)d_out;
    float* part = (float*)d_ws;   // 32*512*128*4 = 8 MB << ws_size

    // grid = 32 n-tiles x 32 i-chunks = 1024 blocks (4/CU, 16 waves/CU)
    kan_main<<<dim3(1024), dim3(256), 0, stream>>>(
        x, grid, coef, scale_base, scale_sp, mask, part);
    kan_reduce<<<dim3(BATCH * OUT_DIM / 256), dim3(256), 0, stream>>>(part, out);
}